// Round 4
// baseline (8364.677 us; speedup 1.0000x reference)
//
#include <hip/hip_runtime.h>

// Teacher-forced GRU + additive attention decoder, MI355X. FLOAT32 I/O.
// Round 4: counter-based sync (1 poller/block, fire-and-forget atomicAdd),
// scores over 200 threads (4-way k-split), pointwise+dec merged into wave0
// via shuffles, gi_x prefetched into LDS. NSL=16 (512 blocks, 2/CU).
#define BB    32
#define TDEC  400
#define TENC  800
#define EDIM  256
#define GDIM  256
#define ADIM  128
#define IDIM  80
#define G3    768
#define NSL   16    // slices (blocks) per batch element
#define SLH   16    // GDIM/NSL h-elements per slice
#define SLT   50    // TENC/NSL encoder timesteps per slice

typedef unsigned short u16;
typedef unsigned int u32;

__device__ __forceinline__ float b2f(u16 u) {
  union { u32 i; float f; } x; x.i = ((u32)u) << 16; return x.f;
}
__device__ __forceinline__ u16 f2b(float f) {
  union { float f; u32 u; } x; x.f = f;
  u32 u = x.u; u += 0x7fffu + ((u >> 16) & 1u);
  return (u16)(u >> 16);
}
// 8 bf16 -> 8 f32 (16B load; works for global and LDS pointers after inlining)
__device__ __forceinline__ void ld8(const u16* p, float* w) {
  const uint4 q = *reinterpret_cast<const uint4*>(p);
  union { u32 i; float f; } c;
  c.i = q.x << 16;          w[0] = c.f;
  c.i = q.x & 0xffff0000u;  w[1] = c.f;
  c.i = q.y << 16;          w[2] = c.f;
  c.i = q.y & 0xffff0000u;  w[3] = c.f;
  c.i = q.z << 16;          w[4] = c.f;
  c.i = q.z & 0xffff0000u;  w[5] = c.f;
  c.i = q.w << 16;          w[6] = c.f;
  c.i = q.w & 0xffff0000u;  w[7] = c.f;
}
__device__ __forceinline__ void ldf8(const float* p, float* w) {
  const float4 a = *reinterpret_cast<const float4*>(p);
  const float4 b = *reinterpret_cast<const float4*>(p + 4);
  w[0] = a.x; w[1] = a.y; w[2] = a.z; w[3] = a.w;
  w[4] = b.x; w[5] = b.y; w[6] = b.z; w[7] = b.w;
}
__device__ __forceinline__ float fsigmoid(float x) {
  return __builtin_amdgcn_rcpf(1.f + __expf(-x));
}
__device__ __forceinline__ float ftanh(float x) {
  float e = __expf(2.f * x);
  return 1.f - 2.f * __builtin_amdgcn_rcpf(e + 1.f);
}
// Relaxed agent-scope atomics: bypass L1/L2 to LLC, no cache invalidation.
__device__ __forceinline__ void ast(float* p, float v) {
  __hip_atomic_store(p, v, __ATOMIC_RELAXED, __HIP_MEMORY_SCOPE_AGENT);
}
__device__ __forceinline__ float ald(const float* p) {
  return __hip_atomic_load(p, __ATOMIC_RELAXED, __HIP_MEMORY_SCOPE_AGENT);
}

// ---------------- K1: gi_x[b][t][g] = x_t . W_ih[:, :80] + b_ih (bf16 out) -----
__global__ __launch_bounds__(256) void k_gix(
    const float* __restrict__ gt, const float* __restrict__ W_ih,
    const float* __restrict__ b_ih, u16* __restrict__ gi_x) {
  __shared__ float sc_x[8][IDIM];
  const int tid = threadIdx.x;
  const int b = blockIdx.x / 50;
  const int t0 = (blockIdx.x % 50) * 8;
  for (int idx = tid; idx < 8 * IDIM; idx += 256) {
    int row = idx / IDIM, col = idx % IDIM;
    sc_x[row][col] = gt[((size_t)b * TDEC + t0 + row) * IDIM + col];
  }
  __syncthreads();
  for (int kk = 0; kk < 3; ++kk) {
    const int g = tid + 256 * kk;
    const float* wrow = W_ih + (size_t)g * 336;
    float acc[8] = {0,0,0,0,0,0,0,0};
    #pragma unroll 2
    for (int k8 = 0; k8 < IDIM / 8; ++k8) {
      float w[8]; ldf8(wrow + (k8 << 3), w);
      #pragma unroll
      for (int tt = 0; tt < 8; ++tt) {
        const float* x = &sc_x[tt][k8 << 3];
        acc[tt] += w[0]*x[0] + w[1]*x[1] + w[2]*x[2] + w[3]*x[3]
                 + w[4]*x[4] + w[5]*x[5] + w[6]*x[6] + w[7]*x[7];
      }
    }
    const float bias = b_ih[g];
    #pragma unroll
    for (int tt = 0; tt < 8; ++tt)
      gi_x[((size_t)b * TDEC + t0 + tt) * G3 + g] = f2b(acc[tt] + bias);
  }
}

// ------- K2: enc_proj (bf16) + bf16 copy of enc_feat ---------------------------
__global__ __launch_bounds__(256) void k_encp(
    const float* __restrict__ enc_feat, const float* __restrict__ W_enc,
    u16* __restrict__ encp, u16* __restrict__ enc_bf) {
  __shared__ float sc_x[16][EDIM];
  const int tid = threadIdx.x;
  const int b = blockIdx.x / 50;
  const int te0 = (blockIdx.x % 50) * 16;
  for (int idx = tid; idx < 16 * EDIM; idx += 256) {
    int row = idx >> 8, col = idx & 255;
    sc_x[row][col] = enc_feat[((size_t)b * TENC + te0 + row) * EDIM + col];
  }
  __syncthreads();
  const int a = tid & 127;
  const int tg = tid >> 7;
  const float* wrow = W_enc + (size_t)a * EDIM;
  float acc[8] = {0,0,0,0,0,0,0,0};
  #pragma unroll 4
  for (int k8 = 0; k8 < EDIM / 8; ++k8) {
    float w[8]; ldf8(wrow + (k8 << 3), w);
    #pragma unroll
    for (int tt = 0; tt < 8; ++tt) {
      const float* x = &sc_x[tg * 8 + tt][k8 << 3];
      acc[tt] += w[0]*x[0] + w[1]*x[1] + w[2]*x[2] + w[3]*x[3]
               + w[4]*x[4] + w[5]*x[5] + w[6]*x[6] + w[7]*x[7];
    }
  }
  #pragma unroll
  for (int tt = 0; tt < 8; ++tt)
    encp[((size_t)b * TENC + te0 + tg * 8 + tt) * ADIM + a] = f2b(acc[tt]);
  for (int idx = tid; idx < 16 * EDIM; idx += 256)
    enc_bf[((size_t)b * TENC + te0) * EDIM + idx] = f2b(sc_x[idx >> 8][idx & 255]);
}

// ---------------- K3: persistent step loop (16 blocks per batch elem) ----------
__global__ __launch_bounds__(256) void k_decode(
    const u16* __restrict__ enc_bf, const float* __restrict__ W_ih,
    const float* __restrict__ W_hh, const float* __restrict__ b_hh,
    const float* __restrict__ W_dec, const float* __restrict__ b_attn,
    const float* __restrict__ v_attn, const u16* __restrict__ gi_x,
    const u16* __restrict__ encp, float* __restrict__ stash,
    float* __restrict__ Xh, float* __restrict__ Xdec,
    float* __restrict__ Xctx, float* __restrict__ Xsum,
    int* __restrict__ cntA, int* __restrict__ cntB,
    float* __restrict__ out_attn) {
  // rows 0..47: W_ih ctx-cols (gate-major), rows 48..95: W_hh. 264 = 256+8 pad.
  __shared__ u16 sW[96 * 264];        // 50688 B
  __shared__ u16 sWd[128 * 24];       // 6144 B (row = 16 used + 8 pad)
  __shared__ float sc_in[512];        // [0..256)=ctx(t-1), [256..512)=h(t-1)
  __shared__ float sc_dec[ADIM];
  __shared__ float sc_g0[48];
  __shared__ float sc_g1[48];
  __shared__ float sc_w[SLT];
  __shared__ float sc_v[ADIM];
  __shared__ float sc_ba[ADIM];
  __shared__ float sc_bhh[48];
  __shared__ float sc_gx[48];

  const int tid = threadIdx.x;
  const int b = blockIdx.x & 31;
  const int j = blockIdx.x >> 5;

  // ---- one-time staging: weights -> LDS bf16 ----
  for (int it = tid; it < 96 * 32; it += 256) {
    const int q = it >> 5, k0 = (it & 31) << 3;
    const float* src;
    if (q < 48) {
      const int gate = q >> 4, i = q & 15;
      src = W_ih + (size_t)(gate * 256 + SLH * j + i) * 336 + 80 + k0;
    } else {
      const int r = q - 48, gate = r >> 4, i = r & 15;
      src = W_hh + (size_t)(gate * 256 + SLH * j + i) * 256 + k0;
    }
    float w[8]; ldf8(src, w);
    uint4 pk;
    pk.x = (u32)f2b(w[0]) | ((u32)f2b(w[1]) << 16);
    pk.y = (u32)f2b(w[2]) | ((u32)f2b(w[3]) << 16);
    pk.z = (u32)f2b(w[4]) | ((u32)f2b(w[5]) << 16);
    pk.w = (u32)f2b(w[6]) | ((u32)f2b(w[7]) << 16);
    *reinterpret_cast<uint4*>(&sW[q * 264 + k0]) = pk;
  }
  for (int it = tid; it < 128 * 2; it += 256) {
    const int q = it >> 1, k0 = (it & 1) << 3;
    float w[8]; ldf8(W_dec + (size_t)q * GDIM + SLH * j + k0, w);
    uint4 pk;
    pk.x = (u32)f2b(w[0]) | ((u32)f2b(w[1]) << 16);
    pk.y = (u32)f2b(w[2]) | ((u32)f2b(w[3]) << 16);
    pk.z = (u32)f2b(w[4]) | ((u32)f2b(w[5]) << 16);
    pk.w = (u32)f2b(w[6]) | ((u32)f2b(w[7]) << 16);
    *reinterpret_cast<uint4*>(&sWd[q * 24 + k0]) = pk;
  }
  if (tid < ADIM) { sc_v[tid] = v_attn[tid]; sc_ba[tid] = b_attn[tid]; }
  if (tid < 48) {
    const int gate = tid >> 4, i = tid & 15;
    sc_bhh[tid] = b_hh[gate * 256 + SLH * j + i];
    // prefetch gi_x for t=0
    const int grow = gate * 256 + SLH * j + i;
    sc_gx[tid] = b2f(gi_x[((size_t)b * TDEC + 0) * G3 + grow]);
  }
  sc_in[tid] = 0.f;
  sc_in[256 + tid] = 0.f;
  __syncthreads();

  const int q1 = tid >> 1, h1 = tid & 1;            // phase1: lds row / k-half
  const int lane = tid & 63;

  for (int t = 0; t < TDEC; ++t) {
    // -------- phase 1: gate dots from LDS weights ----------------------------
    if (tid < 192) {
      const u16* wp = &sW[q1 * 264 + h1 * 128];
      const float* act = sc_in + ((q1 < 48) ? 0 : 256) + h1 * 128;
      float acc = 0.f;
      #pragma unroll 8
      for (int k8 = 0; k8 < 16; ++k8) {
        float w[8]; ld8(wp + (k8 << 3), w);
        const float* a8 = act + (k8 << 3);
        acc += w[0]*a8[0] + w[1]*a8[1] + w[2]*a8[2] + w[3]*a8[3]
             + w[4]*a8[4] + w[5]*a8[5] + w[6]*a8[6] + w[7]*a8[7];
      }
      acc += __shfl_xor(acc, 1);
      if (h1 == 0) {
        if (q1 < 48) sc_g0[q1] = acc + sc_gx[q1];
        else         sc_g1[q1 - 48] = acc + sc_bhh[q1 - 48];
      }
    }
    __syncthreads();  // B1
    // -------- wave0: GRU pointwise + dec partial (shuffle broadcast) ---------
    if (tid < 64) {
      float hval = 0.f;
      if (lane < SLH) {
        const float gr = sc_g0[lane] + sc_g1[lane];
        const float gz = sc_g0[SLH + lane] + sc_g1[SLH + lane];
        const float rr = fsigmoid(gr);
        const float zz = fsigmoid(gz);
        const float nn = ftanh(sc_g0[2 * SLH + lane] + rr * sc_g1[2 * SLH + lane]);
        const float hp = sc_in[256 + SLH * j + lane];
        hval = (1.f - zz) * nn + zz * hp;
        ast(&Xh[b * GDIM + SLH * j + lane], hval);
        stash[((size_t)b * TDEC + t) * 512 + SLH * j + lane] = hval;
      }
      float hn[16];
      #pragma unroll
      for (int k = 0; k < 16; ++k) hn[k] = __shfl(hval, k);
      #pragma unroll
      for (int r2 = 0; r2 < 2; ++r2) {
        const int a = lane + 64 * r2;
        const u16* wp = &sWd[a * 24];
        float w0[8], w1[8];
        ld8(wp, w0); ld8(wp + 8, w1);
        float acc = 0.f;
        #pragma unroll
        for (int k = 0; k < 8; ++k) acc += w0[k] * hn[k];
        #pragma unroll
        for (int k = 0; k < 8; ++k) acc += w1[k] * hn[8 + k];
        ast(&Xdec[(b * NSL + j) * ADIM + a], acc);
      }
    }
    __syncthreads();  // B3: drains Xh/Xdec/stash to LLC
    if (tid == 0) {
      (void)__hip_atomic_fetch_add(&cntA[b], 1, __ATOMIC_RELAXED,
                                   __HIP_MEMORY_SCOPE_AGENT);
      while (__hip_atomic_load(&cntA[b], __ATOMIC_RELAXED,
                               __HIP_MEMORY_SCOPE_AGENT) < NSL * (t + 1)) {}
    }
    __syncthreads();  // B4: sync A done
    const float hreg = ald(&Xh[b * GDIM + tid]);   // h(t), overlaps dec loads
    if (tid < ADIM) {
      float d = sc_ba[tid];
      #pragma unroll
      for (int jj = 0; jj < NSL; ++jj) d += ald(&Xdec[(b * NSL + jj) * ADIM + tid]);
      sc_dec[tid] = d;
    }
    __syncthreads();  // B5: sc_dec ready
    // -------- phase 2a: scores, 4-way k-split over 200 threads ---------------
    if (tid < 200) {
      const int te = tid >> 2, q = tid & 3;
      const u16* ep = encp + ((size_t)b * TENC + SLT * j + te) * ADIM + q * 32;
      const float* dp = sc_dec + q * 32;
      const float* vp = sc_v + q * 32;
      float s = 0.f;
      #pragma unroll
      for (int k8 = 0; k8 < 4; ++k8) {
        float w[8]; ld8(ep + (k8 << 3), w);
        #pragma unroll
        for (int i = 0; i < 8; ++i) {
          const int a = (k8 << 3) + i;
          s += ftanh(w[i] + dp[a]) * vp[a];
        }
      }
      s += __shfl_xor(s, 1);
      s += __shfl_xor(s, 2);
      if (q == 0) sc_w[te] = __expf(s);  // |s| <= ||v||_1 ~ 5: max-free safe
    } else if (tid < 248) {  // prefetch gi_x(t+1) into LDS
      const int gl = tid - 200;
      const int grow = (gl >> 4) * 256 + SLH * j + (gl & 15);
      const int tn = (t + 1 < TDEC) ? t + 1 : t;
      sc_gx[gl] = b2f(gi_x[((size_t)b * TDEC + tn) * G3 + grow]);
    }
    sc_in[256 + tid] = hreg;  // h(t) for next phase1 (read after B9)
    __syncthreads();  // B6: sc_w ready
    if (tid < 64) {  // partial exp-sum over this slice
      float v = (tid < SLT) ? sc_w[tid] : 0.f;
      #pragma unroll
      for (int off = 1; off < 64; off <<= 1) v += __shfl_xor(v, off);
      if (tid == 0) ast(&Xsum[b * NSL + j], v);
    }
    {  // phase 2b: unnormalized ctx partial (bf16 enc copy, coalesced columns)
      const u16* ef = enc_bf + ((size_t)b * TENC + SLT * j) * EDIM + tid;
      float pc = 0.f;
      #pragma unroll 10
      for (int te = 0; te < SLT; ++te)
        pc += sc_w[te] * b2f(ef[(size_t)te * EDIM]);
      ast(&Xctx[(b * NSL + j) * EDIM + tid], pc);
    }
    __syncthreads();  // B7: drains Xsum/Xctx to LLC
    if (tid == 0) {
      (void)__hip_atomic_fetch_add(&cntB[b], 1, __ATOMIC_RELAXED,
                                   __HIP_MEMORY_SCOPE_AGENT);
      while (__hip_atomic_load(&cntB[b], __ATOMIC_RELAXED,
                               __HIP_MEMORY_SCOPE_AGENT) < NSL * (t + 1)) {}
    }
    __syncthreads();  // B8: sync B done
    {
      float S = 0.f;
      #pragma unroll
      for (int jj = 0; jj < NSL; ++jj) S += ald(&Xsum[b * NSL + jj]);
      float c = 0.f;
      #pragma unroll
      for (int jj = 0; jj < NSL; ++jj) c += ald(&Xctx[(b * NSL + jj) * EDIM + tid]);
      const float invS = __builtin_amdgcn_rcpf(S);
      const float cv = c * invS;
      sc_in[tid] = cv;  // ctx(t) for next step
      if (j == 0) stash[((size_t)b * TDEC + t) * 512 + EDIM + tid] = cv;
      if (tid < SLT)
        out_attn[((size_t)b * TDEC + t) * TENC + SLT * j + tid] =
            sc_w[tid] * invS;
    }
    __syncthreads();  // B9
  }
}

// ---------------- K4: pred = log_softmax([h;ctx] . W_out^T + b_out) ------------
__global__ __launch_bounds__(256) void k_pred(
    const float* __restrict__ stash, const float* __restrict__ W_out,
    const float* __restrict__ b_out, float* __restrict__ out_pred) {
  __shared__ float sc_s[4][512];
  __shared__ float sc_lp[2][4][IDIM];
  __shared__ float sc_l[4][IDIM];
  __shared__ float sc_lse[4];
  const int tid = threadIdx.x;
  const int b = blockIdx.x / 100;
  const int t0 = (blockIdx.x % 100) * 4;
  for (int idx = tid; idx < 4 * 512; idx += 256)
    sc_s[idx >> 9][idx & 511] = stash[((size_t)b * TDEC + t0) * 512 + idx];
  __syncthreads();
  const int o = tid & 127, kh = tid >> 7;
  if (o < IDIM) {
    const float* wrow = W_out + (size_t)o * 512 + kh * 256;
    float acc[4] = {0,0,0,0};
    #pragma unroll 4
    for (int k8 = 0; k8 < 32; ++k8) {
      float w[8]; ldf8(wrow + (k8 << 3), w);
      #pragma unroll
      for (int tt = 0; tt < 4; ++tt) {
        const float* x = &sc_s[tt][kh * 256 + (k8 << 3)];
        acc[tt] += w[0]*x[0] + w[1]*x[1] + w[2]*x[2] + w[3]*x[3]
                 + w[4]*x[4] + w[5]*x[5] + w[6]*x[6] + w[7]*x[7];
      }
    }
    #pragma unroll
    for (int tt = 0; tt < 4; ++tt) sc_lp[kh][tt][o] = acc[tt];
  }
  __syncthreads();
  if (tid < IDIM) {
    const float bb = b_out[tid];
    #pragma unroll
    for (int tt = 0; tt < 4; ++tt)
      sc_l[tt][tid] = sc_lp[0][tt][tid] + sc_lp[1][tt][tid] + bb;
  }
  __syncthreads();
  {
    const int w = tid >> 6, lane = tid & 63;
    const float a0 = sc_l[w][lane];
    const float a1 = (lane < IDIM - 64) ? sc_l[w][lane + 64] : -1e30f;
    float m = fmaxf(a0, a1);
    #pragma unroll
    for (int off = 1; off < 64; off <<= 1) m = fmaxf(m, __shfl_xor(m, off));
    float e = __expf(a0 - m) + ((lane < IDIM - 64) ? __expf(a1 - m) : 0.f);
    #pragma unroll
    for (int off = 1; off < 64; off <<= 1) e += __shfl_xor(e, off);
    if (lane == 0) sc_lse[w] = m + __logf(e);
  }
  __syncthreads();
  for (int idx = tid; idx < 4 * IDIM; idx += 256) {
    const int tt = idx / IDIM, oo = idx % IDIM;
    out_pred[((size_t)b * TDEC + t0 + tt) * IDIM + oo] =
        sc_l[tt][oo] - sc_lse[tt];
  }
}

extern "C" void kernel_launch(void* const* d_in, const int* in_sizes, int n_in,
                              void* d_out, int out_size, void* d_ws, size_t ws_size,
                              hipStream_t stream) {
  const float* enc_feat = (const float*)d_in[0];
  const float* gt       = (const float*)d_in[1];
  const float* W_ih     = (const float*)d_in[2];
  const float* W_hh     = (const float*)d_in[3];
  const float* b_ih     = (const float*)d_in[4];
  const float* b_hh     = (const float*)d_in[5];
  const float* W_enc    = (const float*)d_in[6];
  const float* W_dec    = (const float*)d_in[7];
  const float* b_attn   = (const float*)d_in[8];
  const float* v_attn   = (const float*)d_in[9];
  const float* W_out    = (const float*)d_in[10];
  const float* b_out    = (const float*)d_in[11];
  float* out_pred = (float*)d_out;
  float* out_attn = out_pred + (size_t)BB * TDEC * IDIM;

  char* ws = (char*)d_ws;
  size_t off = 0;
  u16* gi_x   = (u16*)(ws + off);   off += (size_t)BB * TDEC * G3 * 2;
  u16* encp   = (u16*)(ws + off);   off += (size_t)BB * TENC * ADIM * 2;
  u16* enc_bf = (u16*)(ws + off);   off += (size_t)BB * TENC * EDIM * 2;
  float* stash= (float*)(ws + off); off += (size_t)BB * TDEC * 512 * 4;
  float* Xh   = (float*)(ws + off); off += (size_t)BB * GDIM * 4;
  float* Xdec = (float*)(ws + off); off += (size_t)BB * NSL * ADIM * 4;
  float* Xctx = (float*)(ws + off); off += (size_t)BB * NSL * EDIM * 4;
  float* Xsum = (float*)(ws + off); off += (size_t)BB * NSL * 4;
  int* cntA   = (int*)(ws + off);   off += (size_t)BB * 4;
  int* cntB   = (int*)(ws + off);   off += (size_t)BB * 4;

  hipMemsetAsync(cntA, 0, (size_t)BB * 4 * 2, stream);  // zero A+B counters

  hipLaunchKernelGGL(k_gix, dim3(BB * 50), dim3(256), 0, stream,
                     gt, W_ih, b_ih, gi_x);
  hipLaunchKernelGGL(k_encp, dim3(BB * 50), dim3(256), 0, stream,
                     enc_feat, W_enc, encp, enc_bf);
  hipLaunchKernelGGL(k_decode, dim3(BB * NSL), dim3(256), 0, stream,
                     enc_bf, W_ih, W_hh, b_hh, W_dec, b_attn, v_attn,
                     gi_x, encp, stash, Xh, Xdec, Xctx, Xsum,
                     cntA, cntB, out_attn);
  hipLaunchKernelGGL(k_pred, dim3(BB * 100), dim3(256), 0, stream,
                     stash, W_out, b_out, out_pred);
}

// Round 5
// 4278.698 us; speedup vs baseline: 1.9550x; 1.9550x over previous
//
#include <hip/hip_runtime.h>

// Teacher-forced GRU + additive attention decoder, MI355X. FLOAT32 I/O.
// Round 5: R3-style per-block flag stores (no RMW counters), each flag padded
// to its own 64B line, s_sleep poll backoff. Payload shrink: W_dec held in
// VGPRs (dec_proj computed locally from full h -> no Xdec gather); ctx/sum
// partials accumulated producer-side via global_atomic_add_f32 into
// parity-double-buffered accumulators (1 ald/thread consumer read).
#define BB    32
#define TDEC  400
#define TENC  800
#define EDIM  256
#define GDIM  256
#define ADIM  128
#define IDIM  80
#define G3    768
#define NSL   16    // slices (blocks) per batch element
#define SLH   16    // GDIM/NSL h-elements per slice
#define SLT   50    // TENC/NSL encoder timesteps per slice
#define FSTR  16    // flag stride in ints (64B line each)

typedef unsigned short u16;
typedef unsigned int u32;

__device__ __forceinline__ float b2f(u16 u) {
  union { u32 i; float f; } x; x.i = ((u32)u) << 16; return x.f;
}
__device__ __forceinline__ u16 f2b(float f) {
  union { float f; u32 u; } x; x.f = f;
  u32 u = x.u; u += 0x7fffu + ((u >> 16) & 1u);
  return (u16)(u >> 16);
}
// 8 bf16 -> 8 f32 (16B load; works for global and LDS pointers after inlining)
__device__ __forceinline__ void ld8(const u16* p, float* w) {
  const uint4 q = *reinterpret_cast<const uint4*>(p);
  union { u32 i; float f; } c;
  c.i = q.x << 16;          w[0] = c.f;
  c.i = q.x & 0xffff0000u;  w[1] = c.f;
  c.i = q.y << 16;          w[2] = c.f;
  c.i = q.y & 0xffff0000u;  w[3] = c.f;
  c.i = q.z << 16;          w[4] = c.f;
  c.i = q.z & 0xffff0000u;  w[5] = c.f;
  c.i = q.w << 16;          w[6] = c.f;
  c.i = q.w & 0xffff0000u;  w[7] = c.f;
}
__device__ __forceinline__ void ldf8(const float* p, float* w) {
  const float4 a = *reinterpret_cast<const float4*>(p);
  const float4 b = *reinterpret_cast<const float4*>(p + 4);
  w[0] = a.x; w[1] = a.y; w[2] = a.z; w[3] = a.w;
  w[4] = b.x; w[5] = b.y; w[6] = b.z; w[7] = b.w;
}
__device__ __forceinline__ float fsigmoid(float x) {
  return __builtin_amdgcn_rcpf(1.f + __expf(-x));
}
__device__ __forceinline__ float ftanh(float x) {
  float e = __expf(2.f * x);
  return 1.f - 2.f * __builtin_amdgcn_rcpf(e + 1.f);
}
// Relaxed agent-scope atomics: bypass L1/L2 to LLC, no cache invalidation.
__device__ __forceinline__ void ast(float* p, float v) {
  __hip_atomic_store(p, v, __ATOMIC_RELAXED, __HIP_MEMORY_SCOPE_AGENT);
}
__device__ __forceinline__ float ald(const float* p) {
  return __hip_atomic_load(p, __ATOMIC_RELAXED, __HIP_MEMORY_SCOPE_AGENT);
}
__device__ __forceinline__ void aadd(float* p, float v) {
  (void)__hip_atomic_fetch_add(p, v, __ATOMIC_RELAXED, __HIP_MEMORY_SCOPE_AGENT);
}

// ---------------- K1: gi_x[b][t][g] = x_t . W_ih[:, :80] + b_ih (bf16 out) -----
__global__ __launch_bounds__(256) void k_gix(
    const float* __restrict__ gt, const float* __restrict__ W_ih,
    const float* __restrict__ b_ih, u16* __restrict__ gi_x) {
  __shared__ float sc_x[8][IDIM];
  const int tid = threadIdx.x;
  const int b = blockIdx.x / 50;
  const int t0 = (blockIdx.x % 50) * 8;
  for (int idx = tid; idx < 8 * IDIM; idx += 256) {
    int row = idx / IDIM, col = idx % IDIM;
    sc_x[row][col] = gt[((size_t)b * TDEC + t0 + row) * IDIM + col];
  }
  __syncthreads();
  for (int kk = 0; kk < 3; ++kk) {
    const int g = tid + 256 * kk;
    const float* wrow = W_ih + (size_t)g * 336;
    float acc[8] = {0,0,0,0,0,0,0,0};
    #pragma unroll 2
    for (int k8 = 0; k8 < IDIM / 8; ++k8) {
      float w[8]; ldf8(wrow + (k8 << 3), w);
      #pragma unroll
      for (int tt = 0; tt < 8; ++tt) {
        const float* x = &sc_x[tt][k8 << 3];
        acc[tt] += w[0]*x[0] + w[1]*x[1] + w[2]*x[2] + w[3]*x[3]
                 + w[4]*x[4] + w[5]*x[5] + w[6]*x[6] + w[7]*x[7];
      }
    }
    const float bias = b_ih[g];
    #pragma unroll
    for (int tt = 0; tt < 8; ++tt)
      gi_x[((size_t)b * TDEC + t0 + tt) * G3 + g] = f2b(acc[tt] + bias);
  }
}

// ------- K2: enc_proj (bf16) + bf16 copy of enc_feat ---------------------------
__global__ __launch_bounds__(256) void k_encp(
    const float* __restrict__ enc_feat, const float* __restrict__ W_enc,
    u16* __restrict__ encp, u16* __restrict__ enc_bf) {
  __shared__ float sc_x[16][EDIM];
  const int tid = threadIdx.x;
  const int b = blockIdx.x / 50;
  const int te0 = (blockIdx.x % 50) * 16;
  for (int idx = tid; idx < 16 * EDIM; idx += 256) {
    int row = idx >> 8, col = idx & 255;
    sc_x[row][col] = enc_feat[((size_t)b * TENC + te0 + row) * EDIM + col];
  }
  __syncthreads();
  const int a = tid & 127;
  const int tg = tid >> 7;
  const float* wrow = W_enc + (size_t)a * EDIM;
  float acc[8] = {0,0,0,0,0,0,0,0};
  #pragma unroll 4
  for (int k8 = 0; k8 < EDIM / 8; ++k8) {
    float w[8]; ldf8(wrow + (k8 << 3), w);
    #pragma unroll
    for (int tt = 0; tt < 8; ++tt) {
      const float* x = &sc_x[tg * 8 + tt][k8 << 3];
      acc[tt] += w[0]*x[0] + w[1]*x[1] + w[2]*x[2] + w[3]*x[3]
               + w[4]*x[4] + w[5]*x[5] + w[6]*x[6] + w[7]*x[7];
    }
  }
  #pragma unroll
  for (int tt = 0; tt < 8; ++tt)
    encp[((size_t)b * TENC + te0 + tg * 8 + tt) * ADIM + a] = f2b(acc[tt]);
  for (int idx = tid; idx < 16 * EDIM; idx += 256)
    enc_bf[((size_t)b * TENC + te0) * EDIM + idx] = f2b(sc_x[idx >> 8][idx & 255]);
}

// ---------------- K3: persistent step loop (16 blocks per batch elem) ----------
__global__ __launch_bounds__(256) void k_decode(
    const u16* __restrict__ enc_bf, const float* __restrict__ W_ih,
    const float* __restrict__ W_hh, const float* __restrict__ b_hh,
    const float* __restrict__ W_dec, const float* __restrict__ b_attn,
    const float* __restrict__ v_attn, const u16* __restrict__ gi_x,
    const u16* __restrict__ encp, float* __restrict__ stash,
    float* __restrict__ Xh, float* __restrict__ Xctxacc,
    float* __restrict__ Xsumacc,
    int* __restrict__ flagA, int* __restrict__ flagB,
    float* __restrict__ out_attn) {
  // rows 0..47: W_ih ctx-cols (gate-major), rows 48..95: W_hh. 264 = 256+8 pad.
  __shared__ __align__(16) u16 sW[96 * 264];     // 50688 B
  __shared__ __align__(16) float sc_in[512];     // [0..256)=ctx(t-1), [256..512)=h(t-1)
  __shared__ float sc_dec[ADIM];
  __shared__ float sc_lp[256];
  __shared__ float sc_g0[48];
  __shared__ float sc_g1[48];
  __shared__ float sc_w[SLT];
  __shared__ float sc_v[ADIM];
  __shared__ float sc_ba[ADIM];
  __shared__ float sc_bhh[48];
  __shared__ float sc_gx[48];

  const int tid = threadIdx.x;
  const int b = blockIdx.x & 31;
  const int j = blockIdx.x >> 5;

  // ---- one-time staging: gate weights -> LDS bf16 ----
  for (int it = tid; it < 96 * 32; it += 256) {
    const int q = it >> 5, k0 = (it & 31) << 3;
    const float* src;
    if (q < 48) {
      const int gate = q >> 4, i = q & 15;
      src = W_ih + (size_t)(gate * 256 + SLH * j + i) * 336 + 80 + k0;
    } else {
      const int r = q - 48, gate = r >> 4, i = r & 15;
      src = W_hh + (size_t)(gate * 256 + SLH * j + i) * 256 + k0;
    }
    float w[8]; ldf8(src, w);
    uint4 pk;
    pk.x = (u32)f2b(w[0]) | ((u32)f2b(w[1]) << 16);
    pk.y = (u32)f2b(w[2]) | ((u32)f2b(w[3]) << 16);
    pk.z = (u32)f2b(w[4]) | ((u32)f2b(w[5]) << 16);
    pk.w = (u32)f2b(w[6]) | ((u32)f2b(w[7]) << 16);
    *reinterpret_cast<uint4*>(&sW[q * 264 + k0]) = pk;
  }
  // ---- one-time: this thread's W_dec half-row -> 64 packed VGPRs ----
  const int a_dec = tid & 127, kh_dec = tid >> 7;
  u32 wd[64];
  {
    const float2* wp2 = reinterpret_cast<const float2*>(
        W_dec + (size_t)a_dec * GDIM + kh_dec * 128);
    #pragma unroll
    for (int k = 0; k < 64; ++k) {
      const float2 v = wp2[k];
      wd[k] = (u32)f2b(v.x) | ((u32)f2b(v.y) << 16);
    }
  }
  if (tid < ADIM) { sc_v[tid] = v_attn[tid]; sc_ba[tid] = b_attn[tid]; }
  if (tid < 48) {
    const int gate = tid >> 4, i = tid & 15;
    sc_bhh[tid] = b_hh[gate * 256 + SLH * j + i];
    const int grow = gate * 256 + SLH * j + i;
    sc_gx[tid] = b2f(gi_x[((size_t)b * TDEC + 0) * G3 + grow]);  // t=0 prefetch
  }
  sc_in[tid] = 0.f;
  sc_in[256 + tid] = 0.f;
  __syncthreads();

  const int q1 = tid >> 1, h1 = tid & 1;            // phase1: lds row / k-half

  for (int t = 0; t < TDEC; ++t) {
    const int p = t & 1;
    // -------- phase 1: gate dots from LDS weights ----------------------------
    if (tid < 192) {
      const u16* wp = &sW[q1 * 264 + h1 * 128];
      const float* act = sc_in + ((q1 < 48) ? 0 : 256) + h1 * 128;
      float acc = 0.f;
      #pragma unroll 8
      for (int k8 = 0; k8 < 16; ++k8) {
        float w[8]; ld8(wp + (k8 << 3), w);
        const float* a8 = act + (k8 << 3);
        acc += w[0]*a8[0] + w[1]*a8[1] + w[2]*a8[2] + w[3]*a8[3]
             + w[4]*a8[4] + w[5]*a8[5] + w[6]*a8[6] + w[7]*a8[7];
      }
      acc += __shfl_xor(acc, 1);
      if (h1 == 0) {
        if (q1 < 48) sc_g0[q1] = acc + sc_gx[q1];
        else         sc_g1[q1 - 48] = acc + sc_bhh[q1 - 48];
      }
    }
    __syncthreads();  // B1
    if (tid < SLH) {  // GRU pointwise; publish h slice
      const float gr = sc_g0[tid] + sc_g1[tid];
      const float gz = sc_g0[SLH + tid] + sc_g1[SLH + tid];
      const float rr = fsigmoid(gr);
      const float zz = fsigmoid(gz);
      const float nn = ftanh(sc_g0[2 * SLH + tid] + rr * sc_g1[2 * SLH + tid]);
      const float hp = sc_in[256 + SLH * j + tid];
      const float hn = (1.f - zz) * nn + zz * hp;
      ast(&Xh[b * GDIM + SLH * j + tid], hn);
      stash[((size_t)b * TDEC + t) * 512 + SLH * j + tid] = hn;
    }
    __syncthreads();  // B2: drains Xh/stash to LLC
    if (tid == 0)
      __hip_atomic_store(&flagA[(b * NSL + j) * FSTR], t + 1, __ATOMIC_RELAXED,
                         __HIP_MEMORY_SCOPE_AGENT);
    // -------- wait A: full h(t) published ------------------------------------
    if (tid < NSL) {
      const int* fp = &flagA[(b * NSL + tid) * FSTR];
      while (__hip_atomic_load(fp, __ATOMIC_RELAXED,
                               __HIP_MEMORY_SCOPE_AGENT) < t + 1)
        __builtin_amdgcn_s_sleep(1);
    }
    __syncthreads();  // B3
    sc_in[256 + tid] = ald(&Xh[b * GDIM + tid]);  // h(t)
    // reset the accumulators of parity 1-p (read at t-1; adds resume at t+1)
    if (tid < 16)
      ast(&Xctxacc[(b * 2 + (1 - p)) * EDIM + j * 16 + tid], 0.f);
    if (tid == 16 && j == 0) ast(&Xsumacc[(b * 2 + (1 - p)) * FSTR], 0.f);
    __syncthreads();  // B4: h in LDS
    // -------- dec_proj computed locally from register-held W_dec -------------
    {
      const float* hbase = sc_in + 256 + kh_dec * 128;
      float acc = 0.f;
      #pragma unroll
      for (int k8 = 0; k8 < 16; ++k8) {
        const float4 h0 = *reinterpret_cast<const float4*>(hbase + 8 * k8);
        const float4 h1v = *reinterpret_cast<const float4*>(hbase + 8 * k8 + 4);
        union { u32 i; float f; } lo, hi;
        u32 w2;
        w2 = wd[k8 * 4 + 0]; lo.i = w2 << 16; hi.i = w2 & 0xffff0000u;
        acc += lo.f * h0.x + hi.f * h0.y;
        w2 = wd[k8 * 4 + 1]; lo.i = w2 << 16; hi.i = w2 & 0xffff0000u;
        acc += lo.f * h0.z + hi.f * h0.w;
        w2 = wd[k8 * 4 + 2]; lo.i = w2 << 16; hi.i = w2 & 0xffff0000u;
        acc += lo.f * h1v.x + hi.f * h1v.y;
        w2 = wd[k8 * 4 + 3]; lo.i = w2 << 16; hi.i = w2 & 0xffff0000u;
        acc += lo.f * h1v.z + hi.f * h1v.w;
      }
      sc_lp[tid] = acc;
    }
    __syncthreads();  // B5
    if (tid < ADIM) sc_dec[tid] = sc_lp[tid] + sc_lp[128 + tid] + sc_ba[tid];
    __syncthreads();  // B6: sc_dec ready
    // -------- phase 2a: scores, 4-way k-split over 200 threads ---------------
    if (tid < 200) {
      const int te = tid >> 2, q = tid & 3;
      const u16* ep = encp + ((size_t)b * TENC + SLT * j + te) * ADIM + q * 32;
      const float* dp = sc_dec + q * 32;
      const float* vp = sc_v + q * 32;
      float s = 0.f;
      #pragma unroll
      for (int k8 = 0; k8 < 4; ++k8) {
        float w[8]; ld8(ep + (k8 << 3), w);
        #pragma unroll
        for (int i = 0; i < 8; ++i) {
          const int a = (k8 << 3) + i;
          s += ftanh(w[i] + dp[a]) * vp[a];
        }
      }
      s += __shfl_xor(s, 1);
      s += __shfl_xor(s, 2);
      if (q == 0) sc_w[te] = __expf(s);  // |s| <= ||v||_1 ~ 5: max-free safe
    } else if (tid < 248) {  // prefetch gi_x(t+1) into LDS
      const int gl = tid - 200;
      const int grow = (gl >> 4) * 256 + SLH * j + (gl & 15);
      const int tn = (t + 1 < TDEC) ? t + 1 : t;
      sc_gx[gl] = b2f(gi_x[((size_t)b * TDEC + tn) * G3 + grow]);
    }
    __syncthreads();  // B7: sc_w ready
    if (tid < 64) {  // partial exp-sum over this slice -> atomic accumulate
      float v = (tid < SLT) ? sc_w[tid] : 0.f;
      #pragma unroll
      for (int off = 1; off < 64; off <<= 1) v += __shfl_xor(v, off);
      if (tid == 0) aadd(&Xsumacc[(b * 2 + p) * FSTR], v);
    }
    {  // phase 2b: unnormalized ctx partial -> atomic accumulate
      const u16* ef = enc_bf + ((size_t)b * TENC + SLT * j) * EDIM + tid;
      float pc = 0.f;
      #pragma unroll 10
      for (int te = 0; te < SLT; ++te)
        pc += sc_w[te] * b2f(ef[(size_t)te * EDIM]);
      aadd(&Xctxacc[(b * 2 + p) * EDIM + tid], pc);
    }
    __syncthreads();  // B8: drains atomic adds to LLC
    if (tid == 0)
      __hip_atomic_store(&flagB[(b * NSL + j) * FSTR], t + 1, __ATOMIC_RELAXED,
                         __HIP_MEMORY_SCOPE_AGENT);
    // -------- wait B ---------------------------------------------------------
    if (tid < NSL) {
      const int* fp = &flagB[(b * NSL + tid) * FSTR];
      while (__hip_atomic_load(fp, __ATOMIC_RELAXED,
                               __HIP_MEMORY_SCOPE_AGENT) < t + 1)
        __builtin_amdgcn_s_sleep(1);
    }
    __syncthreads();  // B9
    {
      float s0 = 0.f;
      if ((tid & 63) == 0) s0 = ald(&Xsumacc[(b * 2 + p) * FSTR]);
      const float S = __shfl(s0, 0);
      const float c = ald(&Xctxacc[(b * 2 + p) * EDIM + tid]);
      const float invS = __builtin_amdgcn_rcpf(S);
      const float cv = c * invS;
      sc_in[tid] = cv;  // ctx(t) for next step
      if (j == 0) stash[((size_t)b * TDEC + t) * 512 + EDIM + tid] = cv;
      if (tid < SLT)
        out_attn[((size_t)b * TDEC + t) * TENC + SLT * j + tid] =
            sc_w[tid] * invS;
    }
    __syncthreads();  // B10
  }
}

// ---------------- K4: pred = log_softmax([h;ctx] . W_out^T + b_out) ------------
__global__ __launch_bounds__(256) void k_pred(
    const float* __restrict__ stash, const float* __restrict__ W_out,
    const float* __restrict__ b_out, float* __restrict__ out_pred) {
  __shared__ float sc_s[4][512];
  __shared__ float sc_lp[2][4][IDIM];
  __shared__ float sc_l[4][IDIM];
  __shared__ float sc_lse[4];
  const int tid = threadIdx.x;
  const int b = blockIdx.x / 100;
  const int t0 = (blockIdx.x % 100) * 4;
  for (int idx = tid; idx < 4 * 512; idx += 256)
    sc_s[idx >> 9][idx & 511] = stash[((size_t)b * TDEC + t0) * 512 + idx];
  __syncthreads();
  const int o = tid & 127, kh = tid >> 7;
  if (o < IDIM) {
    const float* wrow = W_out + (size_t)o * 512 + kh * 256;
    float acc[4] = {0,0,0,0};
    #pragma unroll 4
    for (int k8 = 0; k8 < 32; ++k8) {
      float w[8]; ldf8(wrow + (k8 << 3), w);
      #pragma unroll
      for (int tt = 0; tt < 4; ++tt) {
        const float* x = &sc_s[tt][kh * 256 + (k8 << 3)];
        acc[tt] += w[0]*x[0] + w[1]*x[1] + w[2]*x[2] + w[3]*x[3]
                 + w[4]*x[4] + w[5]*x[5] + w[6]*x[6] + w[7]*x[7];
      }
    }
    #pragma unroll
    for (int tt = 0; tt < 4; ++tt) sc_lp[kh][tt][o] = acc[tt];
  }
  __syncthreads();
  if (tid < IDIM) {
    const float bb = b_out[tid];
    #pragma unroll
    for (int tt = 0; tt < 4; ++tt)
      sc_l[tt][tid] = sc_lp[0][tt][tid] + sc_lp[1][tt][tid] + bb;
  }
  __syncthreads();
  {
    const int w = tid >> 6, lane = tid & 63;
    const float a0 = sc_l[w][lane];
    const float a1 = (lane < IDIM - 64) ? sc_l[w][lane + 64] : -1e30f;
    float m = fmaxf(a0, a1);
    #pragma unroll
    for (int off = 1; off < 64; off <<= 1) m = fmaxf(m, __shfl_xor(m, off));
    float e = __expf(a0 - m) + ((lane < IDIM - 64) ? __expf(a1 - m) : 0.f);
    #pragma unroll
    for (int off = 1; off < 64; off <<= 1) e += __shfl_xor(e, off);
    if (lane == 0) sc_lse[w] = m + __logf(e);
  }
  __syncthreads();
  for (int idx = tid; idx < 4 * IDIM; idx += 256) {
    const int tt = idx / IDIM, oo = idx % IDIM;
    out_pred[((size_t)b * TDEC + t0 + tt) * IDIM + oo] =
        sc_l[tt][oo] - sc_lse[tt];
  }
}

extern "C" void kernel_launch(void* const* d_in, const int* in_sizes, int n_in,
                              void* d_out, int out_size, void* d_ws, size_t ws_size,
                              hipStream_t stream) {
  const float* enc_feat = (const float*)d_in[0];
  const float* gt       = (const float*)d_in[1];
  const float* W_ih     = (const float*)d_in[2];
  const float* W_hh     = (const float*)d_in[3];
  const float* b_ih     = (const float*)d_in[4];
  const float* b_hh     = (const float*)d_in[5];
  const float* W_enc    = (const float*)d_in[6];
  const float* W_dec    = (const float*)d_in[7];
  const float* b_attn   = (const float*)d_in[8];
  const float* v_attn   = (const float*)d_in[9];
  const float* W_out    = (const float*)d_in[10];
  const float* b_out    = (const float*)d_in[11];
  float* out_pred = (float*)d_out;
  float* out_attn = out_pred + (size_t)BB * TDEC * IDIM;

  char* ws = (char*)d_ws;
  size_t off = 0;
  u16* gi_x   = (u16*)(ws + off);   off += (size_t)BB * TDEC * G3 * 2;
  u16* encp   = (u16*)(ws + off);   off += (size_t)BB * TENC * ADIM * 2;
  u16* enc_bf = (u16*)(ws + off);   off += (size_t)BB * TENC * EDIM * 2;
  float* stash= (float*)(ws + off); off += (size_t)BB * TDEC * 512 * 4;
  float* Xh   = (float*)(ws + off); off += (size_t)BB * GDIM * 4;
  // ---- zeroed region (one memset): flags + accumulators ----
  char* zbase = ws + off;
  int* flagA    = (int*)(ws + off);   off += (size_t)BB * NSL * FSTR * 4;
  int* flagB    = (int*)(ws + off);   off += (size_t)BB * NSL * FSTR * 4;
  float* Xctxacc= (float*)(ws + off); off += (size_t)BB * 2 * EDIM * 4;
  float* Xsumacc= (float*)(ws + off); off += (size_t)BB * 2 * FSTR * 4;
  const size_t zbytes = (size_t)(ws + off - zbase);

  hipMemsetAsync(zbase, 0, zbytes, stream);

  hipLaunchKernelGGL(k_gix, dim3(BB * 50), dim3(256), 0, stream,
                     gt, W_ih, b_ih, gi_x);
  hipLaunchKernelGGL(k_encp, dim3(BB * 50), dim3(256), 0, stream,
                     enc_feat, W_enc, encp, enc_bf);
  hipLaunchKernelGGL(k_decode, dim3(BB * NSL), dim3(256), 0, stream,
                     enc_bf, W_ih, W_hh, b_hh, W_dec, b_attn, v_attn,
                     gi_x, encp, stash, Xh, Xctxacc, Xsumacc,
                     flagA, flagB, out_attn);
  hipLaunchKernelGGL(k_pred, dim3(BB * 100), dim3(256), 0, stream,
                     stash, W_out, b_out, out_pred);
}

// Round 6
// 3460.247 us; speedup vs baseline: 2.4174x; 1.2365x over previous
//
#include <hip/hip_runtime.h>

// Teacher-forced GRU + additive attention decoder, MI355X. FLOAT32 I/O.
// Round 6: dec_proj partials accumulated PRE-flagA (Dacc atomic-add) so scores
// start right after sync A; encp+enc slices resident in LDS (step-invariant);
// gate weights in registers (quad-split rows); gh computed in sync-B shadow.
#define BB    32
#define TDEC  400
#define TENC  800
#define EDIM  256
#define GDIM  256
#define ADIM  128
#define IDIM  80
#define G3    768
#define NSL   16    // slices (blocks) per batch element
#define SLH   16    // GDIM/NSL h-elements per slice
#define SLT   50    // TENC/NSL encoder timesteps per slice
#define FSTR  16    // flag stride in ints (64B line each)
#define EPST  144   // encp LDS row stride (u16): 16B-aligned, spread banks
#define ETST  58    // enc_t LDS row stride (u16): u32-aligned, gcd(29,32)=1

typedef unsigned short u16;
typedef unsigned int u32;

__device__ __forceinline__ float b2f(u16 u) {
  union { u32 i; float f; } x; x.i = ((u32)u) << 16; return x.f;
}
__device__ __forceinline__ u16 f2b(float f) {
  union { float f; u32 u; } x; x.f = f;
  u32 u = x.u; u += 0x7fffu + ((u >> 16) & 1u);
  return (u16)(u >> 16);
}
// 8 bf16 -> 8 f32 (16B load; global or LDS)
__device__ __forceinline__ void ld8(const u16* p, float* w) {
  const uint4 q = *reinterpret_cast<const uint4*>(p);
  union { u32 i; float f; } c;
  c.i = q.x << 16;          w[0] = c.f;
  c.i = q.x & 0xffff0000u;  w[1] = c.f;
  c.i = q.y << 16;          w[2] = c.f;
  c.i = q.y & 0xffff0000u;  w[3] = c.f;
  c.i = q.z << 16;          w[4] = c.f;
  c.i = q.z & 0xffff0000u;  w[5] = c.f;
  c.i = q.w << 16;          w[6] = c.f;
  c.i = q.w & 0xffff0000u;  w[7] = c.f;
}
__device__ __forceinline__ void ldf8(const float* p, float* w) {
  const float4 a = *reinterpret_cast<const float4*>(p);
  const float4 b = *reinterpret_cast<const float4*>(p + 4);
  w[0] = a.x; w[1] = a.y; w[2] = a.z; w[3] = a.w;
  w[4] = b.x; w[5] = b.y; w[6] = b.z; w[7] = b.w;
}
__device__ __forceinline__ float fsigmoid(float x) {
  return __builtin_amdgcn_rcpf(1.f + __expf(-x));
}
__device__ __forceinline__ float ftanh(float x) {
  float e = __expf(2.f * x);
  return 1.f - 2.f * __builtin_amdgcn_rcpf(e + 1.f);
}
// Relaxed agent-scope atomics: bypass L1/L2 to LLC, no cache invalidation.
__device__ __forceinline__ void ast(float* p, float v) {
  __hip_atomic_store(p, v, __ATOMIC_RELAXED, __HIP_MEMORY_SCOPE_AGENT);
}
__device__ __forceinline__ float ald(const float* p) {
  return __hip_atomic_load(p, __ATOMIC_RELAXED, __HIP_MEMORY_SCOPE_AGENT);
}
__device__ __forceinline__ void aadd(float* p, float v) {
  (void)__hip_atomic_fetch_add(p, v, __ATOMIC_RELAXED, __HIP_MEMORY_SCOPE_AGENT);
}

// ---------------- K1: gi_x[b][t][g] = x_t . W_ih[:, :80] + b_ih (bf16 out) -----
__global__ __launch_bounds__(256) void k_gix(
    const float* __restrict__ gt, const float* __restrict__ W_ih,
    const float* __restrict__ b_ih, u16* __restrict__ gi_x) {
  __shared__ float sc_x[8][IDIM];
  const int tid = threadIdx.x;
  const int b = blockIdx.x / 50;
  const int t0 = (blockIdx.x % 50) * 8;
  for (int idx = tid; idx < 8 * IDIM; idx += 256) {
    int row = idx / IDIM, col = idx % IDIM;
    sc_x[row][col] = gt[((size_t)b * TDEC + t0 + row) * IDIM + col];
  }
  __syncthreads();
  for (int kk = 0; kk < 3; ++kk) {
    const int g = tid + 256 * kk;
    const float* wrow = W_ih + (size_t)g * 336;
    float acc[8] = {0,0,0,0,0,0,0,0};
    #pragma unroll 2
    for (int k8 = 0; k8 < IDIM / 8; ++k8) {
      float w[8]; ldf8(wrow + (k8 << 3), w);
      #pragma unroll
      for (int tt = 0; tt < 8; ++tt) {
        const float* x = &sc_x[tt][k8 << 3];
        acc[tt] += w[0]*x[0] + w[1]*x[1] + w[2]*x[2] + w[3]*x[3]
                 + w[4]*x[4] + w[5]*x[5] + w[6]*x[6] + w[7]*x[7];
      }
    }
    const float bias = b_ih[g];
    #pragma unroll
    for (int tt = 0; tt < 8; ++tt)
      gi_x[((size_t)b * TDEC + t0 + tt) * G3 + g] = f2b(acc[tt] + bias);
  }
}

// ------- K2: enc_proj (bf16) + bf16 copy of enc_feat ---------------------------
__global__ __launch_bounds__(256) void k_encp(
    const float* __restrict__ enc_feat, const float* __restrict__ W_enc,
    u16* __restrict__ encp, u16* __restrict__ enc_bf) {
  __shared__ float sc_x[16][EDIM];
  const int tid = threadIdx.x;
  const int b = blockIdx.x / 50;
  const int te0 = (blockIdx.x % 50) * 16;
  for (int idx = tid; idx < 16 * EDIM; idx += 256) {
    int row = idx >> 8, col = idx & 255;
    sc_x[row][col] = enc_feat[((size_t)b * TENC + te0 + row) * EDIM + col];
  }
  __syncthreads();
  const int a = tid & 127;
  const int tg = tid >> 7;
  const float* wrow = W_enc + (size_t)a * EDIM;
  float acc[8] = {0,0,0,0,0,0,0,0};
  #pragma unroll 4
  for (int k8 = 0; k8 < EDIM / 8; ++k8) {
    float w[8]; ldf8(wrow + (k8 << 3), w);
    #pragma unroll
    for (int tt = 0; tt < 8; ++tt) {
      const float* x = &sc_x[tg * 8 + tt][k8 << 3];
      acc[tt] += w[0]*x[0] + w[1]*x[1] + w[2]*x[2] + w[3]*x[3]
               + w[4]*x[4] + w[5]*x[5] + w[6]*x[6] + w[7]*x[7];
    }
  }
  #pragma unroll
  for (int tt = 0; tt < 8; ++tt)
    encp[((size_t)b * TENC + te0 + tg * 8 + tt) * ADIM + a] = f2b(acc[tt]);
  for (int idx = tid; idx < 16 * EDIM; idx += 256)
    enc_bf[((size_t)b * TENC + te0) * EDIM + idx] = f2b(sc_x[idx >> 8][idx & 255]);
}

// ---------------- K3: persistent step loop (16 blocks per batch elem) ----------
__global__ __launch_bounds__(256) void k_decode(
    const u16* __restrict__ enc_bf, const float* __restrict__ W_ih,
    const float* __restrict__ W_hh, const float* __restrict__ b_hh,
    const float* __restrict__ W_dec, const float* __restrict__ b_attn,
    const float* __restrict__ v_attn, const u16* __restrict__ gi_x,
    const u16* __restrict__ encp, float* __restrict__ stash,
    float* __restrict__ Xh, float* __restrict__ Dacc,
    float* __restrict__ Xctxacc, float* __restrict__ Xsumacc,
    int* __restrict__ flagA, int* __restrict__ flagB,
    float* __restrict__ out_attn) {
  __shared__ __align__(16) u16 encp_lds[SLT * EPST];   // 14400 B
  __shared__ __align__(16) u16 enc_t[EDIM * ETST];     // 29696 B  [e][te]
  __shared__ __align__(16) u16 sWd[128 * 26];          // 6656 B
  __shared__ __align__(16) float sc_in[512];  // [0..256)=ctx(t-1), [256..512)=h
  __shared__ float sc_dec[ADIM];
  __shared__ float sc_g0[48];   // W_ihc.ctx + gi_x
  __shared__ float sc_g1[48];   // W_hh.h + b_hh (computed in sync-B shadow)
  __shared__ float sc_w[56];
  __shared__ float sc_v[ADIM];
  __shared__ float sc_ba[ADIM];
  __shared__ float sc_bhh[48];
  __shared__ float sc_gx[48];

  const int tid = threadIdx.x;
  const int b = blockIdx.x & 31;
  const int j = blockIdx.x >> 5;
  const int lane = tid & 63;

  // ---- one-time: gate weights -> registers (quad-split rows) ----
  // 192 threads: r=tid>>2 in [0,48) gate row, q=tid&3 k-quarter (64 elems).
  u32 wctx[32], whh[32];
  #pragma unroll
  for (int i = 0; i < 32; ++i) { wctx[i] = 0u; whh[i] = 0u; }
  if (tid < 192) {
    const int r = tid >> 2, q = tid & 3;
    const int grow = (r >> 4) * 256 + SLH * j + (r & 15);
    const float2* s1 = reinterpret_cast<const float2*>(
        W_ih + (size_t)grow * 336 + 80 + q * 64);
    const float2* s2 = reinterpret_cast<const float2*>(
        W_hh + (size_t)grow * 256 + q * 64);
    #pragma unroll
    for (int i = 0; i < 32; ++i) {
      const float2 v1 = s1[i], v2 = s2[i];
      wctx[i] = (u32)f2b(v1.x) | ((u32)f2b(v1.y) << 16);
      whh[i]  = (u32)f2b(v2.x) | ((u32)f2b(v2.y) << 16);
    }
  }
  // ---- one-time LDS preloads ----
  for (int idx = tid; idx < SLT * ADIM; idx += 256) {     // encp slice
    const int te = idx >> 7, a = idx & 127;
    encp_lds[te * EPST + a] = encp[((size_t)b * TENC + SLT * j + te) * ADIM + a];
  }
  for (int idx = tid; idx < SLT * EDIM; idx += 256) {     // enc slice, transposed
    const int te = idx >> 8, e = idx & 255;
    enc_t[e * ETST + te] = enc_bf[((size_t)b * TENC + SLT * j + te) * EDIM + e];
  }
  for (int idx = tid; idx < 128 * 16; idx += 256) {       // W_dec col-slice
    const int a = idx >> 4, k = idx & 15;
    sWd[a * 26 + k] = f2b(W_dec[(size_t)a * GDIM + SLH * j + k]);
  }
  if (tid < ADIM) { sc_v[tid] = v_attn[tid]; sc_ba[tid] = b_attn[tid]; }
  if (tid < 48) {
    const int gate = tid >> 4, i = tid & 15;
    const int grow = gate * 256 + SLH * j + i;
    const float bh = b_hh[grow];
    sc_bhh[tid] = bh;
    sc_g1[tid] = bh;                                   // gh(h=0) = b_hh
    sc_gx[tid] = b2f(gi_x[((size_t)b * TDEC + 0) * G3 + grow]);
  }
  sc_in[tid] = 0.f;
  sc_in[256 + tid] = 0.f;
  __syncthreads();

  for (int t = 0; t < TDEC; ++t) {
    const int p = t & 1;
    // -------- G0: ctx-half gate dots from register weights -------------------
    if (tid < 192) {
      const float* act = sc_in + ((tid & 3) << 6);
      float acc = 0.f;
      #pragma unroll
      for (int i = 0; i < 32; ++i) {
        union { u32 u; float f; } lo, hi;
        lo.u = wctx[i] << 16; hi.u = wctx[i] & 0xffff0000u;
        acc += lo.f * act[2 * i] + hi.f * act[2 * i + 1];
      }
      acc += __shfl_xor(acc, 1);
      acc += __shfl_xor(acc, 2);
      if ((tid & 3) == 0) sc_g0[tid >> 2] = acc + sc_gx[tid >> 2];
    }
    __syncthreads();  // B1: sc_g0 ready (sc_g1 from prev step's shadow)
    // -------- wave0: pointwise h + local dec partial -> Dacc -----------------
    if (tid < 64) {
      float hval = 0.f;
      if (lane < SLH) {
        const float gr = sc_g0[lane] + sc_g1[lane];
        const float gz = sc_g0[SLH + lane] + sc_g1[SLH + lane];
        const float rr = fsigmoid(gr);
        const float zz = fsigmoid(gz);
        const float nn = ftanh(sc_g0[2 * SLH + lane] + rr * sc_g1[2 * SLH + lane]);
        const float hp = sc_in[256 + SLH * j + lane];
        hval = (1.f - zz) * nn + zz * hp;
        ast(&Xh[b * GDIM + SLH * j + lane], hval);
      }
      float hn16[16];
      #pragma unroll
      for (int k = 0; k < 16; ++k) hn16[k] = __shfl(hval, k);
      #pragma unroll
      for (int r2 = 0; r2 < 2; ++r2) {
        const int a = lane + 64 * r2;
        const u32* wp = reinterpret_cast<const u32*>(&sWd[a * 26]);
        float acc = 0.f;
        #pragma unroll
        for (int k2 = 0; k2 < 8; ++k2) {
          const u32 w2 = wp[k2];
          union { u32 u; float f; } lo, hi;
          lo.u = w2 << 16; hi.u = w2 & 0xffff0000u;
          acc += lo.f * hn16[2 * k2] + hi.f * hn16[2 * k2 + 1];
        }
        aadd(&Dacc[(b * 2 + p) * ADIM + a], acc);
      }
    }
    __syncthreads();  // B2: drain Xh + Dacc adds
    if (tid == 0)
      __hip_atomic_store(&flagA[(b * NSL + j) * FSTR], t + 1, __ATOMIC_RELAXED,
                         __HIP_MEMORY_SCOPE_AGENT);
    if (tid < NSL) {
      const int* fp = &flagA[(b * NSL + tid) * FSTR];
      while (__hip_atomic_load(fp, __ATOMIC_RELAXED,
                               __HIP_MEMORY_SCOPE_AGENT) < t + 1)
        __builtin_amdgcn_s_sleep(1);
    }
    __syncthreads();  // B3: sync A done
    sc_in[256 + tid] = ald(&Xh[b * GDIM + tid]);          // full h(t) (off-path)
    if (tid < ADIM)
      sc_dec[tid] = ald(&Dacc[(b * 2 + p) * ADIM + tid]) + sc_ba[tid];
    // parity resets for 1-p (consumed at t-1; next adds at t+1)
    if (tid < 16) ast(&Xctxacc[(b * 2 + (1 - p)) * EDIM + j * 16 + tid], 0.f);
    if (j == 0) {
      if (tid >= 128) ast(&Dacc[(b * 2 + (1 - p)) * ADIM + (tid - 128)], 0.f);
      if (tid == 16) ast(&Xsumacc[(b * 2 + (1 - p)) * FSTR], 0.f);
    }
    __syncthreads();  // B4: h in LDS + sc_dec ready
    // -------- sync-B shadow: gh(t) from register weights ---------------------
    if (tid < 192) {
      const float* act = sc_in + 256 + ((tid & 3) << 6);
      float acc = 0.f;
      #pragma unroll
      for (int i = 0; i < 32; ++i) {
        union { u32 u; float f; } lo, hi;
        lo.u = whh[i] << 16; hi.u = whh[i] & 0xffff0000u;
        acc += lo.f * act[2 * i] + hi.f * act[2 * i + 1];
      }
      acc += __shfl_xor(acc, 1);
      acc += __shfl_xor(acc, 2);
      if ((tid & 3) == 0) sc_g1[tid >> 2] = acc + sc_bhh[tid >> 2];
    }
    // -------- scores from LDS encp (4-way k-split, 200 threads) --------------
    if (tid < 200) {
      const int te = tid >> 2, q4 = tid & 3;
      const u16* ep = &encp_lds[te * EPST + q4 * 32];
      const float* dp = sc_dec + q4 * 32;
      const float* vp = sc_v + q4 * 32;
      float s = 0.f;
      #pragma unroll
      for (int k8 = 0; k8 < 4; ++k8) {
        float w[8]; ld8(ep + (k8 << 3), w);
        #pragma unroll
        for (int i = 0; i < 8; ++i) {
          const int a = (k8 << 3) + i;
          s += ftanh(w[i] + dp[a]) * vp[a];
        }
      }
      s += __shfl_xor(s, 1);
      s += __shfl_xor(s, 2);
      if (q4 == 0) sc_w[te] = __expf(s);  // |s| <= ||v||_1 ~ 5: max-free safe
    } else if (tid < 248) {  // prefetch gi_x(t+1) into LDS
      const int gl = tid - 200;
      const int grow = (gl >> 4) * 256 + SLH * j + (gl & 15);
      const int tn = (t + 1 < TDEC) ? t + 1 : t;
      sc_gx[gl] = b2f(gi_x[((size_t)b * TDEC + tn) * G3 + grow]);
    }
    // stash h slice (off critical path)
    if (tid >= 248)
      stash[((size_t)b * TDEC + t) * 512 + SLH * j + (tid - 248) * 2] = 0.f;  // placeholder overwritten below
    __syncthreads();  // B5: sc_w ready
    if (tid < SLH)  // stash h slice (values now stable in sc_in)
      stash[((size_t)b * TDEC + t) * 512 + SLH * j + tid] =
          sc_in[256 + SLH * j + tid];
    if (tid < 64) {  // exp-sum partial for this slice
      float v = (tid < SLT) ? sc_w[tid] : 0.f;
      #pragma unroll
      for (int off = 1; off < 64; off <<= 1) v += __shfl_xor(v, off);
      if (tid == 0) aadd(&Xsumacc[(b * 2 + p) * FSTR], v);
    }
    {  // ctx partial from transposed LDS enc slice (conflict-free u32 reads)
      const u32* et = reinterpret_cast<const u32*>(&enc_t[tid * ETST]);
      float pc = 0.f;
      #pragma unroll
      for (int k2 = 0; k2 < 25; ++k2) {
        const u32 w2 = et[k2];
        union { u32 u; float f; } lo, hi;
        lo.u = w2 << 16; hi.u = w2 & 0xffff0000u;
        pc += sc_w[2 * k2] * lo.f + sc_w[2 * k2 + 1] * hi.f;
      }
      aadd(&Xctxacc[(b * 2 + p) * EDIM + tid], pc);
    }
    __syncthreads();  // B6: drain sum/ctx adds
    if (tid == 0)
      __hip_atomic_store(&flagB[(b * NSL + j) * FSTR], t + 1, __ATOMIC_RELAXED,
                         __HIP_MEMORY_SCOPE_AGENT);
    if (tid < NSL) {
      const int* fp = &flagB[(b * NSL + tid) * FSTR];
      while (__hip_atomic_load(fp, __ATOMIC_RELAXED,
                               __HIP_MEMORY_SCOPE_AGENT) < t + 1)
        __builtin_amdgcn_s_sleep(1);
    }
    __syncthreads();  // B7: sync B done
    {
      float s0 = 0.f;
      if ((tid & 63) == 0) s0 = ald(&Xsumacc[(b * 2 + p) * FSTR]);
      const float S = __shfl(s0, 0);
      const float c = ald(&Xctxacc[(b * 2 + p) * EDIM + tid]);
      const float invS = __builtin_amdgcn_rcpf(S);
      const float cv = c * invS;
      sc_in[tid] = cv;  // ctx(t) for next step
      if (j == 0) stash[((size_t)b * TDEC + t) * 512 + EDIM + tid] = cv;
      if (tid < SLT)
        out_attn[((size_t)b * TDEC + t) * TENC + SLT * j + tid] =
            sc_w[tid] * invS;
    }
    __syncthreads();  // B8
  }
}

// ---------------- K4: pred = log_softmax([h;ctx] . W_out^T + b_out) ------------
__global__ __launch_bounds__(256) void k_pred(
    const float* __restrict__ stash, const float* __restrict__ W_out,
    const float* __restrict__ b_out, float* __restrict__ out_pred) {
  __shared__ float sc_s[4][512];
  __shared__ float sc_lp[2][4][IDIM];
  __shared__ float sc_l[4][IDIM];
  __shared__ float sc_lse[4];
  const int tid = threadIdx.x;
  const int b = blockIdx.x / 100;
  const int t0 = (blockIdx.x % 100) * 4;
  for (int idx = tid; idx < 4 * 512; idx += 256)
    sc_s[idx >> 9][idx & 511] = stash[((size_t)b * TDEC + t0) * 512 + idx];
  __syncthreads();
  const int o = tid & 127, kh = tid >> 7;
  if (o < IDIM) {
    const float* wrow = W_out + (size_t)o * 512 + kh * 256;
    float acc[4] = {0,0,0,0};
    #pragma unroll 4
    for (int k8 = 0; k8 < 32; ++k8) {
      float w[8]; ldf8(wrow + (k8 << 3), w);
      #pragma unroll
      for (int tt = 0; tt < 4; ++tt) {
        const float* x = &sc_s[tt][kh * 256 + (k8 << 3)];
        acc[tt] += w[0]*x[0] + w[1]*x[1] + w[2]*x[2] + w[3]*x[3]
                 + w[4]*x[4] + w[5]*x[5] + w[6]*x[6] + w[7]*x[7];
      }
    }
    #pragma unroll
    for (int tt = 0; tt < 4; ++tt) sc_lp[kh][tt][o] = acc[tt];
  }
  __syncthreads();
  if (tid < IDIM) {
    const float bb = b_out[tid];
    #pragma unroll
    for (int tt = 0; tt < 4; ++tt)
      sc_l[tt][tid] = sc_lp[0][tt][tid] + sc_lp[1][tt][tid] + bb;
  }
  __syncthreads();
  {
    const int w = tid >> 6, lane = tid & 63;
    const float a0 = sc_l[w][lane];
    const float a1 = (lane < IDIM - 64) ? sc_l[w][lane + 64] : -1e30f;
    float m = fmaxf(a0, a1);
    #pragma unroll
    for (int off = 1; off < 64; off <<= 1) m = fmaxf(m, __shfl_xor(m, off));
    float e = __expf(a0 - m) + ((lane < IDIM - 64) ? __expf(a1 - m) : 0.f);
    #pragma unroll
    for (int off = 1; off < 64; off <<= 1) e += __shfl_xor(e, off);
    if (lane == 0) sc_lse[w] = m + __logf(e);
  }
  __syncthreads();
  for (int idx = tid; idx < 4 * IDIM; idx += 256) {
    const int tt = idx / IDIM, oo = idx % IDIM;
    out_pred[((size_t)b * TDEC + t0 + tt) * IDIM + oo] =
        sc_l[tt][oo] - sc_lse[tt];
  }
}

extern "C" void kernel_launch(void* const* d_in, const int* in_sizes, int n_in,
                              void* d_out, int out_size, void* d_ws, size_t ws_size,
                              hipStream_t stream) {
  const float* enc_feat = (const float*)d_in[0];
  const float* gt       = (const float*)d_in[1];
  const float* W_ih     = (const float*)d_in[2];
  const float* W_hh     = (const float*)d_in[3];
  const float* b_ih     = (const float*)d_in[4];
  const float* b_hh     = (const float*)d_in[5];
  const float* W_enc    = (const float*)d_in[6];
  const float* W_dec    = (const float*)d_in[7];
  const float* b_attn   = (const float*)d_in[8];
  const float* v_attn   = (const float*)d_in[9];
  const float* W_out    = (const float*)d_in[10];
  const float* b_out    = (const float*)d_in[11];
  float* out_pred = (float*)d_out;
  float* out_attn = out_pred + (size_t)BB * TDEC * IDIM;

  char* ws = (char*)d_ws;
  size_t off = 0;
  u16* gi_x   = (u16*)(ws + off);   off += (size_t)BB * TDEC * G3 * 2;
  u16* encp   = (u16*)(ws + off);   off += (size_t)BB * TENC * ADIM * 2;
  u16* enc_bf = (u16*)(ws + off);   off += (size_t)BB * TENC * EDIM * 2;
  float* stash= (float*)(ws + off); off += (size_t)BB * TDEC * 512 * 4;
  float* Xh   = (float*)(ws + off); off += (size_t)BB * GDIM * 4;
  // ---- zeroed region (one memset): flags + accumulators ----
  char* zbase = ws + off;
  int* flagA    = (int*)(ws + off);   off += (size_t)BB * NSL * FSTR * 4;
  int* flagB    = (int*)(ws + off);   off += (size_t)BB * NSL * FSTR * 4;
  float* Dacc   = (float*)(ws + off); off += (size_t)BB * 2 * ADIM * 4;
  float* Xctxacc= (float*)(ws + off); off += (size_t)BB * 2 * EDIM * 4;
  float* Xsumacc= (float*)(ws + off); off += (size_t)BB * 2 * FSTR * 4;
  const size_t zbytes = (size_t)(ws + off - zbase);

  hipMemsetAsync(zbase, 0, zbytes, stream);

  hipLaunchKernelGGL(k_gix, dim3(BB * 50), dim3(256), 0, stream,
                     gt, W_ih, b_ih, gi_x);
  hipLaunchKernelGGL(k_encp, dim3(BB * 50), dim3(256), 0, stream,
                     enc_feat, W_enc, encp, enc_bf);
  hipLaunchKernelGGL(k_decode, dim3(BB * NSL), dim3(256), 0, stream,
                     enc_bf, W_ih, W_hh, b_hh, W_dec, b_attn, v_attn,
                     gi_x, encp, stash, Xh, Dacc, Xctxacc, Xsumacc,
                     flagA, flagB, out_attn);
  hipLaunchKernelGGL(k_pred, dim3(BB * 100), dim3(256), 0, stream,
                     stash, W_out, b_out, out_pred);
}